// Round 3
// baseline (752.638 us; speedup 1.0000x reference)
//
#include <hip/hip_runtime.h>

// GCNEncoder: 2x GCNConv(64->64) + BatchNorm + ELU + global_mean_pool
// N=50000, E=800000, D=64, G=64. Inputs f32/int32, output f32.
// R17 366.7 (parallel scan) -> R18 324.1 (gather float4 4-slot lanes) ->
// R19 284.2 (bucketed counting-sort CSR build, atomic scatter killed).
// R19 profile: top-5 all harness fillBuffer (workspace re-poison, untimed).
// Remaining arithmetic: gather 2x~28us (VGPR=12 -> no loads in flight,
// latency-bound), mm64 2x~15us (200MB redundant W restage), bnstats+pool
// ~13us of pure re-reads.
// R20: (1) gather inner step widened to 16 neighbors, 4 named float4 loads
// in flight; (2) matmuls 16 rows/block (W traffic /4); (3) BN-stats fused
// into gather1 (64-replica scratch), pool fused into gather2 (16-replica).

constexpr int GGRAPHS = 64;
constexpr int EPB = 8192;  // edges per partition block

// cnt[g] via per-block LDS histogram (batch sorted -> storms stay in LDS)
__global__ void cnt_kernel(const int* __restrict__ batch, int* __restrict__ cnt, int n) {
  __shared__ int h[GGRAPHS];
  int t = threadIdx.x;
  if (t < GGRAPHS) h[t] = 0;
  __syncthreads();
  for (int i = blockIdx.x * 256 + t; i < n; i += gridDim.x * 256) {
    int g = batch[i];
    if ((unsigned)g < (unsigned)GGRAPHS) atomicAdd(&h[g], 1);
  }
  __syncthreads();
  if (t < GGRAPHS && h[t] > 0) atomicAdd(&cnt[t], h[t]);
}

// P1: per-block bucket histogram. hist[b*nblk + blk] = #edges of block blk
// with dst in bucket b (bucket = dst>>8, nbuck <= 256 for n <= 65536).
__global__ void phist_kernel(const int* __restrict__ dst, int* __restrict__ hist,
                             int E, int n, int nblk, int nbuck) {
  __shared__ int h[256];
  int t = threadIdx.x;
  h[t] = 0;
  __syncthreads();
  int e0 = blockIdx.x * EPB;
  int e1 = e0 + EPB < E ? e0 + EPB : E;
  for (int i = e0 + t; i < e1; i += 256) {
    int d = dst[i];
    if ((unsigned)d < (unsigned)n) atomicAdd(&h[d >> 8], 1);
  }
  __syncthreads();
  if (t < nbuck) hist[t * nblk + blockIdx.x] = h[t];
}

// scan pass 1: per-256-tile exclusive scan; out[i]=local excl, bsum[b]=tile total.
__global__ void scan1_kernel(const int* __restrict__ in, int* __restrict__ out,
                             int* __restrict__ bsum, int n) {
  __shared__ int tmp[256];
  int t = threadIdx.x;
  int i = blockIdx.x * 256 + t;
  int v = (i < n) ? in[i] : 0;
  tmp[t] = v;
  __syncthreads();
#pragma unroll
  for (int off = 1; off < 256; off <<= 1) {
    int a = (t >= off) ? tmp[t - off] : 0;
    __syncthreads();
    tmp[t] += a;
    __syncthreads();
  }
  if (i < n) out[i] = tmp[t] - v;  // exclusive
  if (t == 255) bsum[blockIdx.x] = tmp[255];
}

// scan pass 2: 1 block, exclusive scan of bsum[nb] (nb <= 256); bsum[nb] = total.
__global__ void scan2_kernel(int* __restrict__ bsum, int nb) {
  __shared__ int tmp[256];
  int t = threadIdx.x;
  int v = (t < nb) ? bsum[t] : 0;
  tmp[t] = v;
  __syncthreads();
#pragma unroll
  for (int off = 1; off < 256; off <<= 1) {
    int a = (t >= off) ? tmp[t - off] : 0;
    __syncthreads();
    tmp[t] += a;
    __syncthreads();
  }
  if (t < nb) bsum[t] = tmp[t] - v;
  if (t == 255) bsum[nb] = tmp[255];
}

// scan pass 3: data[i] += bsum[tile]; data[S] = grand total.
__global__ void scan_add_kernel(int* __restrict__ data, const int* __restrict__ bsum,
                                int S, int nbt) {
  int i = blockIdx.x * 256 + threadIdx.x;
  if (i < S) data[i] += bsum[blockIdx.x];
  if (i == 0) data[S] = bsum[nbt];
}

// P3: scatter edges into bucket-partitioned array, packed (src<<8)|(dst&255).
__global__ void part_kernel(const int* __restrict__ srcp, const int* __restrict__ dstp,
                            const int* __restrict__ hist, int* __restrict__ part,
                            int E, int n, int nblk, int nbuck) {
  __shared__ int cur[256];
  int t = threadIdx.x;
  if (t < nbuck) cur[t] = hist[t * nblk + blockIdx.x];
  __syncthreads();
  int e0 = blockIdx.x * EPB;
  int e1 = e0 + EPB < E ? e0 + EPB : E;
  for (int i = e0 + t; i < e1; i += 256) {
    int d = dstp[i];
    if ((unsigned)d >= (unsigned)n) continue;
    int s = srcp[i];
    int pos = atomicAdd(&cur[d >> 8], 1);
    part[pos] = (s << 8) | (d & 255);
  }
}

// P4: one block per bucket (256 nodes). LDS degree -> LDS scan -> rowptr/dinv
// coalesced -> col placed via LDS cursors (writes stay in 16KB segment).
__global__ void csr_kernel(const int* __restrict__ part, const int* __restrict__ hist,
                           int* __restrict__ rowptr, float* __restrict__ dinv,
                           int* __restrict__ col, int n, int nblk, int nbuck) {
  __shared__ int degL[256], scn[256], cur[256];
  int t = threadIdx.x;
  int b = blockIdx.x;
  degL[t] = 0;
  cur[t] = 0;
  __syncthreads();
  int base = hist[b * nblk];
  int end = hist[(b + 1) * nblk];  // hist[S] = total for last bucket
  for (int i = base + t; i < end; i += 256) atomicAdd(&degL[part[i] & 255], 1);
  __syncthreads();
  int dv = degL[t];
  scn[t] = dv;
  __syncthreads();
#pragma unroll
  for (int off = 1; off < 256; off <<= 1) {
    int a = (t >= off) ? scn[t - off] : 0;
    __syncthreads();
    scn[t] += a;
    __syncthreads();
  }
  int excl = scn[t] - dv;
  int node = (b << 8) + t;
  if (node < n) {
    rowptr[node] = base + excl;
    dinv[node] = rsqrtf((float)dv + 1.0f);
  }
  if (b == nbuck - 1 && t == 0) rowptr[n] = end;
  scn[t] = excl;
  __syncthreads();
  for (int i = base + t; i < end; i += 256) {
    int u = part[i];
    int d = u & 255;
    int k = atomicAdd(&cur[d], 1);
    col[base + scn[d] + k] = u >> 8;
  }
}

// Y[n,64] = X[n,64] @ W[64,64]; 16 rows/block (4 rows/thread), W staged once.
__global__ void mm64_kernel(const float* __restrict__ X, const float* __restrict__ W,
                            float* __restrict__ Y, int n) {
  __shared__ float Ws[64][64];
  __shared__ float xs[16][64];
  int tid = threadIdx.x;
  for (int i = tid; i < 64 * 64; i += 256) Ws[i >> 6][i & 63] = W[i];
  int c = tid & 63, rg = tid >> 6;
  int row0 = blockIdx.x * 16;
#pragma unroll
  for (int q = 0; q < 4; ++q) {
    int r = rg + q * 4;
    int row = row0 + r;
    xs[r][c] = (row < n) ? X[(size_t)row * 64 + c] : 0.0f;
  }
  __syncthreads();
  float a0 = 0.f, a1 = 0.f, a2 = 0.f, a3 = 0.f;
#pragma unroll
  for (int k = 0; k < 64; ++k) {
    float wv = Ws[k][c];
    a0 = fmaf(xs[rg * 4 + 0][k], wv, a0);
    a1 = fmaf(xs[rg * 4 + 1][k], wv, a1);
    a2 = fmaf(xs[rg * 4 + 2][k], wv, a2);
    a3 = fmaf(xs[rg * 4 + 3][k], wv, a3);
  }
  int r0 = row0 + rg * 4;
  if (r0 + 0 < n) Y[(size_t)(r0 + 0) * 64 + c] = a0;
  if (r0 + 1 < n) Y[(size_t)(r0 + 1) * 64 + c] = a1;
  if (r0 + 2 < n) Y[(size_t)(r0 + 2) * 64 + c] = a2;
  if (r0 + 3 < n) Y[(size_t)(r0 + 3) * 64 + c] = a3;
}

// BN affine + ELU on X rows, then @W; same 16-rows/block structure.
__global__ void bn_elu_mm64_kernel(const float* __restrict__ X, const float* __restrict__ W,
                                   const float* __restrict__ ss, float* __restrict__ Y, int n) {
  __shared__ float Ws[64][64];
  __shared__ float xs[16][64];
  int tid = threadIdx.x;
  for (int i = tid; i < 64 * 64; i += 256) Ws[i >> 6][i & 63] = W[i];
  int c = tid & 63, rg = tid >> 6;
  float sc = ss[c], sh = ss[64 + c];
  int row0 = blockIdx.x * 16;
#pragma unroll
  for (int q = 0; q < 4; ++q) {
    int r = rg + q * 4;
    int row = row0 + r;
    float v = 0.0f;
    if (row < n) {
      v = X[(size_t)row * 64 + c] * sc + sh;
      v = v > 0.0f ? v : expm1f(v);
    }
    xs[r][c] = v;
  }
  __syncthreads();
  float a0 = 0.f, a1 = 0.f, a2 = 0.f, a3 = 0.f;
#pragma unroll
  for (int k = 0; k < 64; ++k) {
    float wv = Ws[k][c];
    a0 = fmaf(xs[rg * 4 + 0][k], wv, a0);
    a1 = fmaf(xs[rg * 4 + 1][k], wv, a1);
    a2 = fmaf(xs[rg * 4 + 2][k], wv, a2);
    a3 = fmaf(xs[rg * 4 + 3][k], wv, a3);
  }
  int r0 = row0 + rg * 4;
  if (r0 + 0 < n) Y[(size_t)(r0 + 0) * 64 + c] = a0;
  if (r0 + 1 < n) Y[(size_t)(r0 + 1) * 64 + c] = a1;
  if (r0 + 2 < n) Y[(size_t)(r0 + 2) * 64 + c] = a2;
  if (r0 + 3 < n) Y[(size_t)(r0 + 3) * 64 + c] = a3;
}

// Gather core: 1 wave/row, lanes = 4 neighbor-slots x 16 channel-quads.
// 16 neighbors per step with 4 NAMED float4 loads -> 4 row-streams in flight.
// Tail slots masked via staged w=0 (j=0 loads hit cached H row 0).
__device__ __forceinline__ float4 gcn_gather_core(
    const int* __restrict__ rowptr, const int* __restrict__ col,
    const float* __restrict__ dinv, const float4* __restrict__ H4,
    int row, int lane, int sub, int cg, bool valid) {
  float4 acc = make_float4(0.f, 0.f, 0.f, 0.f);
  int p0 = 0, p1 = 0;
  if (valid) { p0 = rowptr[row]; p1 = rowptr[row + 1]; }
  for (int base = p0; base < p1; base += 64) {
    int myp = base + lane;
    int j = (myp < p1) ? col[myp] : 0;
    float w = (myp < p1) ? dinv[j] : 0.0f;
    int m = p1 - base;
    m = m < 64 ? m : 64;
    for (int k = 0; k < m; k += 16) {
      int j0 = __shfl(j, k + sub);
      float w0 = __shfl(w, k + sub);
      int j1 = __shfl(j, k + 4 + sub);
      float w1 = __shfl(w, k + 4 + sub);
      int j2 = __shfl(j, k + 8 + sub);
      float w2 = __shfl(w, k + 8 + sub);
      int j3 = __shfl(j, k + 12 + sub);
      float w3 = __shfl(w, k + 12 + sub);
      float4 h0 = H4[(size_t)j0 * 16 + cg];
      float4 h1 = H4[(size_t)j1 * 16 + cg];
      float4 h2 = H4[(size_t)j2 * 16 + cg];
      float4 h3 = H4[(size_t)j3 * 16 + cg];
      acc.x = fmaf(h0.x, w0, acc.x);
      acc.y = fmaf(h0.y, w0, acc.y);
      acc.z = fmaf(h0.z, w0, acc.z);
      acc.w = fmaf(h0.w, w0, acc.w);
      acc.x = fmaf(h1.x, w1, acc.x);
      acc.y = fmaf(h1.y, w1, acc.y);
      acc.z = fmaf(h1.z, w1, acc.z);
      acc.w = fmaf(h1.w, w1, acc.w);
      acc.x = fmaf(h2.x, w2, acc.x);
      acc.y = fmaf(h2.y, w2, acc.y);
      acc.z = fmaf(h2.z, w2, acc.z);
      acc.w = fmaf(h2.w, w2, acc.w);
      acc.x = fmaf(h3.x, w3, acc.x);
      acc.y = fmaf(h3.y, w3, acc.y);
      acc.z = fmaf(h3.z, w3, acc.z);
      acc.w = fmaf(h3.w, w3, acc.w);
    }
  }
  acc.x += __shfl_xor(acc.x, 16);
  acc.y += __shfl_xor(acc.y, 16);
  acc.z += __shfl_xor(acc.z, 16);
  acc.w += __shfl_xor(acc.w, 16);
  acc.x += __shfl_xor(acc.x, 32);
  acc.y += __shfl_xor(acc.y, 32);
  acc.z += __shfl_xor(acc.z, 32);
  acc.w += __shfl_xor(acc.w, 32);
  return acc;
}

// gather + BN-stat accumulation (64-replica scratch bnsR[64][128]).
__global__ void gather_bn_kernel(const int* __restrict__ rowptr, const int* __restrict__ col,
                                 const float* __restrict__ dinv, const float* __restrict__ H,
                                 const float* __restrict__ b, float* __restrict__ OUT,
                                 float* __restrict__ bnsR, int n) {
  int wave = threadIdx.x >> 6;
  int lane = threadIdx.x & 63;
  int row = blockIdx.x * 4 + wave;
  bool valid = row < n;
  int sub = lane >> 4;
  int cg = lane & 15;
  const float4* __restrict__ H4 = (const float4*)H;
  float4 acc = gcn_gather_core(rowptr, col, dinv, H4, row, lane, sub, cg, valid);
  float4 o = make_float4(0.f, 0.f, 0.f, 0.f);
  if (valid) {
    float di = dinv[row];
    float d2 = di * di;
    float4 self = H4[(size_t)row * 16 + cg];
    float4 bb = ((const float4*)b)[cg];
    o.x = fmaf(acc.x, di, fmaf(self.x, d2, bb.x));
    o.y = fmaf(acc.y, di, fmaf(self.y, d2, bb.y));
    o.z = fmaf(acc.z, di, fmaf(self.z, d2, bb.z));
    o.w = fmaf(acc.w, di, fmaf(self.w, d2, bb.w));
    if (sub == 0) ((float4*)OUT)[(size_t)row * 16 + cg] = o;
  }
  __shared__ float sA[4][64], sB[4][64];
  if (sub == 0) {
    sA[wave][4 * cg + 0] = o.x;
    sA[wave][4 * cg + 1] = o.y;
    sA[wave][4 * cg + 2] = o.z;
    sA[wave][4 * cg + 3] = o.w;
    sB[wave][4 * cg + 0] = o.x * o.x;
    sB[wave][4 * cg + 1] = o.y * o.y;
    sB[wave][4 * cg + 2] = o.z * o.z;
    sB[wave][4 * cg + 3] = o.w * o.w;
  }
  __syncthreads();
  int t = threadIdx.x;
  if (t < 64) {
    float s = sA[0][t] + sA[1][t] + sA[2][t] + sA[3][t];
    float s2 = sB[0][t] + sB[1][t] + sB[2][t] + sB[3][t];
    float* d = bnsR + (size_t)(blockIdx.x & 63) * 128;
    atomicAdd(&d[t], s);
    atomicAdd(&d[64 + t], s2);
  }
}

// gather + pool accumulation (16-replica scratch poolR[16][4096]).
__global__ void gather_pool_kernel(const int* __restrict__ rowptr, const int* __restrict__ col,
                                   const float* __restrict__ dinv, const float* __restrict__ H,
                                   const float* __restrict__ b, float* __restrict__ OUT,
                                   const int* __restrict__ batch, float* __restrict__ poolR,
                                   int n) {
  int wave = threadIdx.x >> 6;
  int lane = threadIdx.x & 63;
  int row = blockIdx.x * 4 + wave;
  if (row >= n) return;
  int sub = lane >> 4;
  int cg = lane & 15;
  const float4* __restrict__ H4 = (const float4*)H;
  float4 acc = gcn_gather_core(rowptr, col, dinv, H4, row, lane, sub, cg, true);
  float di = dinv[row];
  float d2 = di * di;
  float4 self = H4[(size_t)row * 16 + cg];
  float4 bb = ((const float4*)b)[cg];
  float4 o;
  o.x = fmaf(acc.x, di, fmaf(self.x, d2, bb.x));
  o.y = fmaf(acc.y, di, fmaf(self.y, d2, bb.y));
  o.z = fmaf(acc.z, di, fmaf(self.z, d2, bb.z));
  o.w = fmaf(acc.w, di, fmaf(self.w, d2, bb.w));
  if (sub == 0) {
    ((float4*)OUT)[(size_t)row * 16 + cg] = o;
    int g = batch[row];
    if ((unsigned)g < (unsigned)GGRAPHS) {
      float* d = poolR + (size_t)(blockIdx.x & 15) * 4096 + g * 64 + 4 * cg;
      atomicAdd(d + 0, o.x);
      atomicAdd(d + 1, o.y);
      atomicAdd(d + 2, o.z);
      atomicAdd(d + 3, o.w);
    }
  }
}

// reduce 64 BN replicas -> scale/shift
__global__ void bn_final_kernel(const float* __restrict__ bnsR, const float* __restrict__ gamma,
                                const float* __restrict__ beta, float* __restrict__ ss, int n) {
  __shared__ float red[128];
  int t = threadIdx.x;  // 128 threads
  float s = 0.0f;
  for (int r = 0; r < 64; ++r) s += bnsR[r * 128 + t];
  red[t] = s;
  __syncthreads();
  if (t < 64) {
    float inv_n = 1.0f / (float)n;
    float mu = red[t] * inv_n;
    float var = red[64 + t] * inv_n - mu * mu;
    var = fmaxf(var, 0.0f);
    float sc = gamma[t] * rsqrtf(var + 1e-5f);
    ss[t] = sc;
    ss[64 + t] = beta[t] - mu * sc;
  }
}

// reduce 16 pool replicas, divide by count
__global__ void pool_final_kernel(const float* __restrict__ poolR, const int* __restrict__ cnt,
                                  float* __restrict__ out) {
  int idx = blockIdx.x * 256 + threadIdx.x;  // 4096 total
  float s = 0.0f;
  for (int r = 0; r < 16; ++r) s += poolR[r * 4096 + idx];
  int g = idx >> 6;
  float c = (float)cnt[g];
  out[idx] = s / fmaxf(c, 1.0f);
}

extern "C" void kernel_launch(void* const* d_in, const int* in_sizes, int n_in,
                              void* d_out, int out_size, void* d_ws, size_t ws_size,
                              hipStream_t stream) {
  const float* x = (const float*)d_in[0];
  const int* ei = (const int*)d_in[1];
  const int* batch = (const int*)d_in[2];
  const float* W1 = (const float*)d_in[3];
  const float* b1 = (const float*)d_in[4];
  const float* gamma = (const float*)d_in[5];
  const float* beta = (const float*)d_in[6];
  const float* W2 = (const float*)d_in[7];
  const float* b2 = (const float*)d_in[8];

  const int n = in_sizes[0] / 64;
  const int E = in_sizes[1] / 2;
  const int* srcp = ei;
  const int* dstp = ei + E;

  float* ws = (float*)d_ws;
  size_t nf = (size_t)n * 64;
  float* bufA = ws;                   // h1, then h2' (aliases part/hist in preproc)
  float* bufB = ws + nf;              // pre-BN h
  float* dinv = ws + 2 * nf;          // n floats
  float* ss = dinv + n;               // 128
  int* rowptr = (int*)(ss + 128);     // n+1
  int* col = rowptr + n + 1;          // E
  int* bsum = col + E;                // <=257
  float* bnsR = (float*)(bsum + 257); // 64*128   (zero region starts here)
  float* poolR = bnsR + 64 * 128;     // 16*4096
  int* cnti = (int*)(poolR + 16 * 4096);  // 64   (zero region ends here)

  // preprocessing scratch aliased into bufA (free until mm64)
  int* part = (int*)bufA;             // E packed edges
  int* hist = part + E;               // S+1

  float* out = (float*)d_out;  // FLOAT32 output

  size_t zbytes = (size_t)((char*)(cnti + 64) - (char*)bnsR);
  hipMemsetAsync(bnsR, 0, zbytes, stream);

  int blk = 256;
  int nblkP = (E + EPB - 1) / EPB;    // 98 partition blocks
  int nbuck = (n + 255) >> 8;         // 196 buckets (needs n <= 65536)
  int S = nbuck * nblkP;              // 19208 counters
  int nbt = (S + 255) / 256;          // 76 scan tiles (<= 256)
  int gridRows = (n + 3) / 4;
  int gridMM = (n + 15) / 16;

  phist_kernel<<<nblkP, blk, 0, stream>>>(dstp, hist, E, n, nblkP, nbuck);
  cnt_kernel<<<128, blk, 0, stream>>>(batch, cnti, n);
  scan1_kernel<<<nbt, blk, 0, stream>>>(hist, hist, bsum, S);
  scan2_kernel<<<1, blk, 0, stream>>>(bsum, nbt);
  scan_add_kernel<<<nbt, blk, 0, stream>>>(hist, bsum, S, nbt);
  part_kernel<<<nblkP, blk, 0, stream>>>(srcp, dstp, hist, part, E, n, nblkP, nbuck);
  csr_kernel<<<nbuck, blk, 0, stream>>>(part, hist, rowptr, dinv, col, n, nblkP, nbuck);

  mm64_kernel<<<gridMM, blk, 0, stream>>>(x, W1, bufA, n);
  gather_bn_kernel<<<gridRows, blk, 0, stream>>>(rowptr, col, dinv, bufA, b1, bufB, bnsR, n);
  bn_final_kernel<<<1, 128, 0, stream>>>(bnsR, gamma, beta, ss, n);
  bn_elu_mm64_kernel<<<gridMM, blk, 0, stream>>>(bufB, W2, ss, bufA, n);
  gather_pool_kernel<<<gridRows, blk, 0, stream>>>(rowptr, col, dinv, bufA, b2, out, batch,
                                                   poolR, n);
  pool_final_kernel<<<16, blk, 0, stream>>>(poolR, cnti, out + nf);
}

// Round 4
// 402.323 us; speedup vs baseline: 1.8707x; 1.8707x over previous
//
#include <hip/hip_runtime.h>

// GCNEncoder: 2x GCNConv(64->64) + BatchNorm + ELU + global_mean_pool
// N=50000, E=800000, D=64, G=64. Inputs f32/int32, output f32.
// R18 324.1 (gather float4 4-slot lanes) -> R19 284.2 (counting-sort CSR).
// R20 752.6 REGRESSION: 16-rows/block matmuls went 45 -> 230us each with
//   inexplicable 874MB HBM traffic; gather ILP + BN/pool fusion not implicated.
// R21: revert matmuls to R19's known-good 4-rows/block (W restage is
//   L2-resident and cheap); KEEP widened gather ILP (4 named float4 row
//   streams) and fused BN-stats / pool accumulation.

constexpr int GGRAPHS = 64;
constexpr int EPB = 8192;  // edges per partition block

// cnt[g] via per-block LDS histogram (batch sorted -> storms stay in LDS)
__global__ void cnt_kernel(const int* __restrict__ batch, int* __restrict__ cnt, int n) {
  __shared__ int h[GGRAPHS];
  int t = threadIdx.x;
  if (t < GGRAPHS) h[t] = 0;
  __syncthreads();
  for (int i = blockIdx.x * 256 + t; i < n; i += gridDim.x * 256) {
    int g = batch[i];
    if ((unsigned)g < (unsigned)GGRAPHS) atomicAdd(&h[g], 1);
  }
  __syncthreads();
  if (t < GGRAPHS && h[t] > 0) atomicAdd(&cnt[t], h[t]);
}

// P1: per-block bucket histogram. hist[b*nblk + blk] = #edges of block blk
// with dst in bucket b (bucket = dst>>8, nbuck <= 256 for n <= 65536).
__global__ void phist_kernel(const int* __restrict__ dst, int* __restrict__ hist,
                             int E, int n, int nblk, int nbuck) {
  __shared__ int h[256];
  int t = threadIdx.x;
  h[t] = 0;
  __syncthreads();
  int e0 = blockIdx.x * EPB;
  int e1 = e0 + EPB < E ? e0 + EPB : E;
  for (int i = e0 + t; i < e1; i += 256) {
    int d = dst[i];
    if ((unsigned)d < (unsigned)n) atomicAdd(&h[d >> 8], 1);
  }
  __syncthreads();
  if (t < nbuck) hist[t * nblk + blockIdx.x] = h[t];
}

// scan pass 1: per-256-tile exclusive scan; out[i]=local excl, bsum[b]=tile total.
__global__ void scan1_kernel(const int* __restrict__ in, int* __restrict__ out,
                             int* __restrict__ bsum, int n) {
  __shared__ int tmp[256];
  int t = threadIdx.x;
  int i = blockIdx.x * 256 + t;
  int v = (i < n) ? in[i] : 0;
  tmp[t] = v;
  __syncthreads();
#pragma unroll
  for (int off = 1; off < 256; off <<= 1) {
    int a = (t >= off) ? tmp[t - off] : 0;
    __syncthreads();
    tmp[t] += a;
    __syncthreads();
  }
  if (i < n) out[i] = tmp[t] - v;  // exclusive
  if (t == 255) bsum[blockIdx.x] = tmp[255];
}

// scan pass 2: 1 block, exclusive scan of bsum[nb] (nb <= 256); bsum[nb] = total.
__global__ void scan2_kernel(int* __restrict__ bsum, int nb) {
  __shared__ int tmp[256];
  int t = threadIdx.x;
  int v = (t < nb) ? bsum[t] : 0;
  tmp[t] = v;
  __syncthreads();
#pragma unroll
  for (int off = 1; off < 256; off <<= 1) {
    int a = (t >= off) ? tmp[t - off] : 0;
    __syncthreads();
    tmp[t] += a;
    __syncthreads();
  }
  if (t < nb) bsum[t] = tmp[t] - v;
  if (t == 255) bsum[nb] = tmp[255];
}

// scan pass 3: data[i] += bsum[tile]; data[S] = grand total.
__global__ void scan_add_kernel(int* __restrict__ data, const int* __restrict__ bsum,
                                int S, int nbt) {
  int i = blockIdx.x * 256 + threadIdx.x;
  if (i < S) data[i] += bsum[blockIdx.x];
  if (i == 0) data[S] = bsum[nbt];
}

// P3: scatter edges into bucket-partitioned array, packed (src<<8)|(dst&255).
__global__ void part_kernel(const int* __restrict__ srcp, const int* __restrict__ dstp,
                            const int* __restrict__ hist, int* __restrict__ part,
                            int E, int n, int nblk, int nbuck) {
  __shared__ int cur[256];
  int t = threadIdx.x;
  if (t < nbuck) cur[t] = hist[t * nblk + blockIdx.x];
  __syncthreads();
  int e0 = blockIdx.x * EPB;
  int e1 = e0 + EPB < E ? e0 + EPB : E;
  for (int i = e0 + t; i < e1; i += 256) {
    int d = dstp[i];
    if ((unsigned)d >= (unsigned)n) continue;
    int s = srcp[i];
    int pos = atomicAdd(&cur[d >> 8], 1);
    part[pos] = (s << 8) | (d & 255);
  }
}

// P4: one block per bucket (256 nodes). LDS degree -> LDS scan -> rowptr/dinv
// coalesced -> col placed via LDS cursors (writes stay in 16KB segment).
__global__ void csr_kernel(const int* __restrict__ part, const int* __restrict__ hist,
                           int* __restrict__ rowptr, float* __restrict__ dinv,
                           int* __restrict__ col, int n, int nblk, int nbuck) {
  __shared__ int degL[256], scn[256], cur[256];
  int t = threadIdx.x;
  int b = blockIdx.x;
  degL[t] = 0;
  cur[t] = 0;
  __syncthreads();
  int base = hist[b * nblk];
  int end = hist[(b + 1) * nblk];  // hist[S] = total for last bucket
  for (int i = base + t; i < end; i += 256) atomicAdd(&degL[part[i] & 255], 1);
  __syncthreads();
  int dv = degL[t];
  scn[t] = dv;
  __syncthreads();
#pragma unroll
  for (int off = 1; off < 256; off <<= 1) {
    int a = (t >= off) ? scn[t - off] : 0;
    __syncthreads();
    scn[t] += a;
    __syncthreads();
  }
  int excl = scn[t] - dv;
  int node = (b << 8) + t;
  if (node < n) {
    rowptr[node] = base + excl;
    dinv[node] = rsqrtf((float)dv + 1.0f);
  }
  if (b == nbuck - 1 && t == 0) rowptr[n] = end;
  scn[t] = excl;
  __syncthreads();
  for (int i = base + t; i < end; i += 256) {
    int u = part[i];
    int d = u & 255;
    int k = atomicAdd(&cur[d], 1);
    col[base + scn[d] + k] = u >> 8;
  }
}

// Y[n,64] = X[n,64] @ W[64,64]; block = 4 rows x 64 cols (R19 known-good)
__global__ void mm64_kernel(const float* __restrict__ X, const float* __restrict__ W,
                            float* __restrict__ Y, int n) {
  __shared__ float Ws[64][64];
  __shared__ float xs[4][64];
  int tid = threadIdx.x;
  for (int i = tid; i < 64 * 64; i += 256) Ws[i >> 6][i & 63] = W[i];
  int rr = tid >> 6, c = tid & 63;
  int row = blockIdx.x * 4 + rr;
  xs[rr][c] = (row < n) ? X[(size_t)row * 64 + c] : 0.0f;
  __syncthreads();
  float acc = 0.0f;
#pragma unroll
  for (int k = 0; k < 64; ++k) acc = fmaf(xs[rr][k], Ws[k][c], acc);
  if (row < n) Y[(size_t)row * 64 + c] = acc;
}

// BN affine + ELU on X rows, then @W (R19 known-good 4-row form)
__global__ void bn_elu_mm64_kernel(const float* __restrict__ X, const float* __restrict__ W,
                                   const float* __restrict__ ss, float* __restrict__ Y, int n) {
  __shared__ float Ws[64][64];
  __shared__ float xs[4][64];
  int tid = threadIdx.x;
  for (int i = tid; i < 64 * 64; i += 256) Ws[i >> 6][i & 63] = W[i];
  int rr = tid >> 6, c = tid & 63;
  int row = blockIdx.x * 4 + rr;
  float v = 0.0f;
  if (row < n) {
    v = X[(size_t)row * 64 + c] * ss[c] + ss[64 + c];
    v = v > 0.0f ? v : expm1f(v);
  }
  xs[rr][c] = v;
  __syncthreads();
  float acc = 0.0f;
#pragma unroll
  for (int k = 0; k < 64; ++k) acc = fmaf(xs[rr][k], Ws[k][c], acc);
  if (row < n) Y[(size_t)row * 64 + c] = acc;
}

// Gather core: 1 wave/row, lanes = 4 neighbor-slots x 16 channel-quads.
// 16 neighbors per step with 4 NAMED float4 loads -> 4 row-streams in flight.
// Tail slots masked via staged w=0 (j=0 loads hit cached H row 0).
__device__ __forceinline__ float4 gcn_gather_core(
    const int* __restrict__ rowptr, const int* __restrict__ col,
    const float* __restrict__ dinv, const float4* __restrict__ H4,
    int row, int lane, int sub, int cg, bool valid) {
  float4 acc = make_float4(0.f, 0.f, 0.f, 0.f);
  int p0 = 0, p1 = 0;
  if (valid) { p0 = rowptr[row]; p1 = rowptr[row + 1]; }
  for (int base = p0; base < p1; base += 64) {
    int myp = base + lane;
    int j = (myp < p1) ? col[myp] : 0;
    float w = (myp < p1) ? dinv[j] : 0.0f;
    int m = p1 - base;
    m = m < 64 ? m : 64;
    for (int k = 0; k < m; k += 16) {
      int j0 = __shfl(j, k + sub);
      float w0 = __shfl(w, k + sub);
      int j1 = __shfl(j, k + 4 + sub);
      float w1 = __shfl(w, k + 4 + sub);
      int j2 = __shfl(j, k + 8 + sub);
      float w2 = __shfl(w, k + 8 + sub);
      int j3 = __shfl(j, k + 12 + sub);
      float w3 = __shfl(w, k + 12 + sub);
      float4 h0 = H4[(size_t)j0 * 16 + cg];
      float4 h1 = H4[(size_t)j1 * 16 + cg];
      float4 h2 = H4[(size_t)j2 * 16 + cg];
      float4 h3 = H4[(size_t)j3 * 16 + cg];
      acc.x = fmaf(h0.x, w0, acc.x);
      acc.y = fmaf(h0.y, w0, acc.y);
      acc.z = fmaf(h0.z, w0, acc.z);
      acc.w = fmaf(h0.w, w0, acc.w);
      acc.x = fmaf(h1.x, w1, acc.x);
      acc.y = fmaf(h1.y, w1, acc.y);
      acc.z = fmaf(h1.z, w1, acc.z);
      acc.w = fmaf(h1.w, w1, acc.w);
      acc.x = fmaf(h2.x, w2, acc.x);
      acc.y = fmaf(h2.y, w2, acc.y);
      acc.z = fmaf(h2.z, w2, acc.z);
      acc.w = fmaf(h2.w, w2, acc.w);
      acc.x = fmaf(h3.x, w3, acc.x);
      acc.y = fmaf(h3.y, w3, acc.y);
      acc.z = fmaf(h3.z, w3, acc.z);
      acc.w = fmaf(h3.w, w3, acc.w);
    }
  }
  acc.x += __shfl_xor(acc.x, 16);
  acc.y += __shfl_xor(acc.y, 16);
  acc.z += __shfl_xor(acc.z, 16);
  acc.w += __shfl_xor(acc.w, 16);
  acc.x += __shfl_xor(acc.x, 32);
  acc.y += __shfl_xor(acc.y, 32);
  acc.z += __shfl_xor(acc.z, 32);
  acc.w += __shfl_xor(acc.w, 32);
  return acc;
}

// gather + BN-stat accumulation (64-replica scratch bnsR[64][128]).
__global__ void gather_bn_kernel(const int* __restrict__ rowptr, const int* __restrict__ col,
                                 const float* __restrict__ dinv, const float* __restrict__ H,
                                 const float* __restrict__ b, float* __restrict__ OUT,
                                 float* __restrict__ bnsR, int n) {
  int wave = threadIdx.x >> 6;
  int lane = threadIdx.x & 63;
  int row = blockIdx.x * 4 + wave;
  bool valid = row < n;
  int sub = lane >> 4;
  int cg = lane & 15;
  const float4* __restrict__ H4 = (const float4*)H;
  float4 acc = gcn_gather_core(rowptr, col, dinv, H4, row, lane, sub, cg, valid);
  float4 o = make_float4(0.f, 0.f, 0.f, 0.f);
  if (valid) {
    float di = dinv[row];
    float d2 = di * di;
    float4 self = H4[(size_t)row * 16 + cg];
    float4 bb = ((const float4*)b)[cg];
    o.x = fmaf(acc.x, di, fmaf(self.x, d2, bb.x));
    o.y = fmaf(acc.y, di, fmaf(self.y, d2, bb.y));
    o.z = fmaf(acc.z, di, fmaf(self.z, d2, bb.z));
    o.w = fmaf(acc.w, di, fmaf(self.w, d2, bb.w));
    if (sub == 0) ((float4*)OUT)[(size_t)row * 16 + cg] = o;
  }
  __shared__ float sA[4][64], sB[4][64];
  if (sub == 0) {
    sA[wave][4 * cg + 0] = o.x;
    sA[wave][4 * cg + 1] = o.y;
    sA[wave][4 * cg + 2] = o.z;
    sA[wave][4 * cg + 3] = o.w;
    sB[wave][4 * cg + 0] = o.x * o.x;
    sB[wave][4 * cg + 1] = o.y * o.y;
    sB[wave][4 * cg + 2] = o.z * o.z;
    sB[wave][4 * cg + 3] = o.w * o.w;
  }
  __syncthreads();
  int t = threadIdx.x;
  if (t < 64) {
    float s = sA[0][t] + sA[1][t] + sA[2][t] + sA[3][t];
    float s2 = sB[0][t] + sB[1][t] + sB[2][t] + sB[3][t];
    float* d = bnsR + (size_t)(blockIdx.x & 63) * 128;
    atomicAdd(&d[t], s);
    atomicAdd(&d[64 + t], s2);
  }
}

// gather + pool accumulation (16-replica scratch poolR[16][4096]).
__global__ void gather_pool_kernel(const int* __restrict__ rowptr, const int* __restrict__ col,
                                   const float* __restrict__ dinv, const float* __restrict__ H,
                                   const float* __restrict__ b, float* __restrict__ OUT,
                                   const int* __restrict__ batch, float* __restrict__ poolR,
                                   int n) {
  int wave = threadIdx.x >> 6;
  int lane = threadIdx.x & 63;
  int row = blockIdx.x * 4 + wave;
  if (row >= n) return;
  int sub = lane >> 4;
  int cg = lane & 15;
  const float4* __restrict__ H4 = (const float4*)H;
  float4 acc = gcn_gather_core(rowptr, col, dinv, H4, row, lane, sub, cg, true);
  float di = dinv[row];
  float d2 = di * di;
  float4 self = H4[(size_t)row * 16 + cg];
  float4 bb = ((const float4*)b)[cg];
  float4 o;
  o.x = fmaf(acc.x, di, fmaf(self.x, d2, bb.x));
  o.y = fmaf(acc.y, di, fmaf(self.y, d2, bb.y));
  o.z = fmaf(acc.z, di, fmaf(self.z, d2, bb.z));
  o.w = fmaf(acc.w, di, fmaf(self.w, d2, bb.w));
  if (sub == 0) {
    ((float4*)OUT)[(size_t)row * 16 + cg] = o;
    int g = batch[row];
    if ((unsigned)g < (unsigned)GGRAPHS) {
      float* d = poolR + (size_t)(blockIdx.x & 15) * 4096 + g * 64 + 4 * cg;
      atomicAdd(d + 0, o.x);
      atomicAdd(d + 1, o.y);
      atomicAdd(d + 2, o.z);
      atomicAdd(d + 3, o.w);
    }
  }
}

// reduce 64 BN replicas -> scale/shift
__global__ void bn_final_kernel(const float* __restrict__ bnsR, const float* __restrict__ gamma,
                                const float* __restrict__ beta, float* __restrict__ ss, int n) {
  __shared__ float red[128];
  int t = threadIdx.x;  // 128 threads
  float s = 0.0f;
  for (int r = 0; r < 64; ++r) s += bnsR[r * 128 + t];
  red[t] = s;
  __syncthreads();
  if (t < 64) {
    float inv_n = 1.0f / (float)n;
    float mu = red[t] * inv_n;
    float var = red[64 + t] * inv_n - mu * mu;
    var = fmaxf(var, 0.0f);
    float sc = gamma[t] * rsqrtf(var + 1e-5f);
    ss[t] = sc;
    ss[64 + t] = beta[t] - mu * sc;
  }
}

// reduce 16 pool replicas, divide by count
__global__ void pool_final_kernel(const float* __restrict__ poolR, const int* __restrict__ cnt,
                                  float* __restrict__ out) {
  int idx = blockIdx.x * 256 + threadIdx.x;  // 4096 total
  float s = 0.0f;
  for (int r = 0; r < 16; ++r) s += poolR[r * 4096 + idx];
  int g = idx >> 6;
  float c = (float)cnt[g];
  out[idx] = s / fmaxf(c, 1.0f);
}

extern "C" void kernel_launch(void* const* d_in, const int* in_sizes, int n_in,
                              void* d_out, int out_size, void* d_ws, size_t ws_size,
                              hipStream_t stream) {
  const float* x = (const float*)d_in[0];
  const int* ei = (const int*)d_in[1];
  const int* batch = (const int*)d_in[2];
  const float* W1 = (const float*)d_in[3];
  const float* b1 = (const float*)d_in[4];
  const float* gamma = (const float*)d_in[5];
  const float* beta = (const float*)d_in[6];
  const float* W2 = (const float*)d_in[7];
  const float* b2 = (const float*)d_in[8];

  const int n = in_sizes[0] / 64;
  const int E = in_sizes[1] / 2;
  const int* srcp = ei;
  const int* dstp = ei + E;

  float* ws = (float*)d_ws;
  size_t nf = (size_t)n * 64;
  float* bufA = ws;                   // h1, then h2' (aliases part/hist in preproc)
  float* bufB = ws + nf;              // pre-BN h
  float* dinv = ws + 2 * nf;          // n floats
  float* ss = dinv + n;               // 128
  int* rowptr = (int*)(ss + 128);     // n+1
  int* col = rowptr + n + 1;          // E
  int* bsum = col + E;                // <=257
  float* bnsR = (float*)(bsum + 257); // 64*128   (zero region starts here)
  float* poolR = bnsR + 64 * 128;     // 16*4096
  int* cnti = (int*)(poolR + 16 * 4096);  // 64   (zero region ends here)

  // preprocessing scratch aliased into bufA (free until mm64)
  int* part = (int*)bufA;             // E packed edges
  int* hist = part + E;               // S+1

  float* out = (float*)d_out;  // FLOAT32 output

  size_t zbytes = (size_t)((char*)(cnti + 64) - (char*)bnsR);
  hipMemsetAsync(bnsR, 0, zbytes, stream);

  int blk = 256;
  int nblkP = (E + EPB - 1) / EPB;    // 98 partition blocks
  int nbuck = (n + 255) >> 8;         // 196 buckets (needs n <= 65536)
  int S = nbuck * nblkP;              // 19208 counters
  int nbt = (S + 255) / 256;          // 76 scan tiles (<= 256)
  int gridRows = (n + 3) / 4;

  phist_kernel<<<nblkP, blk, 0, stream>>>(dstp, hist, E, n, nblkP, nbuck);
  cnt_kernel<<<128, blk, 0, stream>>>(batch, cnti, n);
  scan1_kernel<<<nbt, blk, 0, stream>>>(hist, hist, bsum, S);
  scan2_kernel<<<1, blk, 0, stream>>>(bsum, nbt);
  scan_add_kernel<<<nbt, blk, 0, stream>>>(hist, bsum, S, nbt);
  part_kernel<<<nblkP, blk, 0, stream>>>(srcp, dstp, hist, part, E, n, nblkP, nbuck);
  csr_kernel<<<nbuck, blk, 0, stream>>>(part, hist, rowptr, dinv, col, n, nblkP, nbuck);

  mm64_kernel<<<gridRows, blk, 0, stream>>>(x, W1, bufA, n);
  gather_bn_kernel<<<gridRows, blk, 0, stream>>>(rowptr, col, dinv, bufA, b1, bufB, bnsR, n);
  bn_final_kernel<<<1, 128, 0, stream>>>(bnsR, gamma, beta, ss, n);
  bn_elu_mm64_kernel<<<gridRows, blk, 0, stream>>>(bufB, W2, ss, bufA, n);
  gather_pool_kernel<<<gridRows, blk, 0, stream>>>(rowptr, col, dinv, bufA, b2, out, batch,
                                                   poolR, n);
  pool_final_kernel<<<16, blk, 0, stream>>>(poolR, cnti, out + nf);
}

// Round 5
// 394.358 us; speedup vs baseline: 1.9085x; 1.0202x over previous
//
#include <hip/hip_runtime.h>

// GCNEncoder: 2x GCNConv(64->64) + BatchNorm + ELU + global_mean_pool
// N=50000, E=800000, D=64, G=64. Inputs f32/int32, output f32.
// R18 324.1 (gather float4 4-slot lanes, k+=4 unroll4) -> R19 284.2
// (counting-sort CSR) -> R20 752.6 REGRESSION (16-row matmuls) ->
// R21 402.3: matmuls fixed, but gathers at ~170us each exposed the R20
//   "hand-widened" inner loop as the real regression: VGPR=24 (can't hold
//   4 float4 streams), compiler serialized shfl->load->fma per stream.
// R22: revert gather inner loop to EXACT R18 form (k+=4, one float4 load
//   per iter, #pragma unroll 4 -> unroller batches 4 shfls+loads). Keep
//   counting-sort CSR, 4-row matmuls, fused BN-stats + pool.

constexpr int GGRAPHS = 64;
constexpr int EPB = 8192;  // edges per partition block

// cnt[g] via per-block LDS histogram (batch sorted -> storms stay in LDS)
__global__ void cnt_kernel(const int* __restrict__ batch, int* __restrict__ cnt, int n) {
  __shared__ int h[GGRAPHS];
  int t = threadIdx.x;
  if (t < GGRAPHS) h[t] = 0;
  __syncthreads();
  for (int i = blockIdx.x * 256 + t; i < n; i += gridDim.x * 256) {
    int g = batch[i];
    if ((unsigned)g < (unsigned)GGRAPHS) atomicAdd(&h[g], 1);
  }
  __syncthreads();
  if (t < GGRAPHS && h[t] > 0) atomicAdd(&cnt[t], h[t]);
}

// P1: per-block bucket histogram. hist[b*nblk + blk] = #edges of block blk
// with dst in bucket b (bucket = dst>>8, nbuck <= 256 for n <= 65536).
__global__ void phist_kernel(const int* __restrict__ dst, int* __restrict__ hist,
                             int E, int n, int nblk, int nbuck) {
  __shared__ int h[256];
  int t = threadIdx.x;
  h[t] = 0;
  __syncthreads();
  int e0 = blockIdx.x * EPB;
  int e1 = e0 + EPB < E ? e0 + EPB : E;
  for (int i = e0 + t; i < e1; i += 256) {
    int d = dst[i];
    if ((unsigned)d < (unsigned)n) atomicAdd(&h[d >> 8], 1);
  }
  __syncthreads();
  if (t < nbuck) hist[t * nblk + blockIdx.x] = h[t];
}

// scan pass 1: per-256-tile exclusive scan; out[i]=local excl, bsum[b]=tile total.
__global__ void scan1_kernel(const int* __restrict__ in, int* __restrict__ out,
                             int* __restrict__ bsum, int n) {
  __shared__ int tmp[256];
  int t = threadIdx.x;
  int i = blockIdx.x * 256 + t;
  int v = (i < n) ? in[i] : 0;
  tmp[t] = v;
  __syncthreads();
#pragma unroll
  for (int off = 1; off < 256; off <<= 1) {
    int a = (t >= off) ? tmp[t - off] : 0;
    __syncthreads();
    tmp[t] += a;
    __syncthreads();
  }
  if (i < n) out[i] = tmp[t] - v;  // exclusive
  if (t == 255) bsum[blockIdx.x] = tmp[255];
}

// scan pass 2: 1 block, exclusive scan of bsum[nb] (nb <= 256); bsum[nb] = total.
__global__ void scan2_kernel(int* __restrict__ bsum, int nb) {
  __shared__ int tmp[256];
  int t = threadIdx.x;
  int v = (t < nb) ? bsum[t] : 0;
  tmp[t] = v;
  __syncthreads();
#pragma unroll
  for (int off = 1; off < 256; off <<= 1) {
    int a = (t >= off) ? tmp[t - off] : 0;
    __syncthreads();
    tmp[t] += a;
    __syncthreads();
  }
  if (t < nb) bsum[t] = tmp[t] - v;
  if (t == 255) bsum[nb] = tmp[255];
}

// scan pass 3: data[i] += bsum[tile]; data[S] = grand total.
__global__ void scan_add_kernel(int* __restrict__ data, const int* __restrict__ bsum,
                                int S, int nbt) {
  int i = blockIdx.x * 256 + threadIdx.x;
  if (i < S) data[i] += bsum[blockIdx.x];
  if (i == 0) data[S] = bsum[nbt];
}

// P3: scatter edges into bucket-partitioned array, packed (src<<8)|(dst&255).
__global__ void part_kernel(const int* __restrict__ srcp, const int* __restrict__ dstp,
                            const int* __restrict__ hist, int* __restrict__ part,
                            int E, int n, int nblk, int nbuck) {
  __shared__ int cur[256];
  int t = threadIdx.x;
  if (t < nbuck) cur[t] = hist[t * nblk + blockIdx.x];
  __syncthreads();
  int e0 = blockIdx.x * EPB;
  int e1 = e0 + EPB < E ? e0 + EPB : E;
  for (int i = e0 + t; i < e1; i += 256) {
    int d = dstp[i];
    if ((unsigned)d >= (unsigned)n) continue;
    int s = srcp[i];
    int pos = atomicAdd(&cur[d >> 8], 1);
    part[pos] = (s << 8) | (d & 255);
  }
}

// P4: one block per bucket (256 nodes). LDS degree -> LDS scan -> rowptr/dinv
// coalesced -> col placed via LDS cursors (writes stay in 16KB segment).
__global__ void csr_kernel(const int* __restrict__ part, const int* __restrict__ hist,
                           int* __restrict__ rowptr, float* __restrict__ dinv,
                           int* __restrict__ col, int n, int nblk, int nbuck) {
  __shared__ int degL[256], scn[256], cur[256];
  int t = threadIdx.x;
  int b = blockIdx.x;
  degL[t] = 0;
  cur[t] = 0;
  __syncthreads();
  int base = hist[b * nblk];
  int end = hist[(b + 1) * nblk];  // hist[S] = total for last bucket
  for (int i = base + t; i < end; i += 256) atomicAdd(&degL[part[i] & 255], 1);
  __syncthreads();
  int dv = degL[t];
  scn[t] = dv;
  __syncthreads();
#pragma unroll
  for (int off = 1; off < 256; off <<= 1) {
    int a = (t >= off) ? scn[t - off] : 0;
    __syncthreads();
    scn[t] += a;
    __syncthreads();
  }
  int excl = scn[t] - dv;
  int node = (b << 8) + t;
  if (node < n) {
    rowptr[node] = base + excl;
    dinv[node] = rsqrtf((float)dv + 1.0f);
  }
  if (b == nbuck - 1 && t == 0) rowptr[n] = end;
  scn[t] = excl;
  __syncthreads();
  for (int i = base + t; i < end; i += 256) {
    int u = part[i];
    int d = u & 255;
    int k = atomicAdd(&cur[d], 1);
    col[base + scn[d] + k] = u >> 8;
  }
}

// Y[n,64] = X[n,64] @ W[64,64]; block = 4 rows x 64 cols (known-good)
__global__ void mm64_kernel(const float* __restrict__ X, const float* __restrict__ W,
                            float* __restrict__ Y, int n) {
  __shared__ float Ws[64][64];
  __shared__ float xs[4][64];
  int tid = threadIdx.x;
  for (int i = tid; i < 64 * 64; i += 256) Ws[i >> 6][i & 63] = W[i];
  int rr = tid >> 6, c = tid & 63;
  int row = blockIdx.x * 4 + rr;
  xs[rr][c] = (row < n) ? X[(size_t)row * 64 + c] : 0.0f;
  __syncthreads();
  float acc = 0.0f;
#pragma unroll
  for (int k = 0; k < 64; ++k) acc = fmaf(xs[rr][k], Ws[k][c], acc);
  if (row < n) Y[(size_t)row * 64 + c] = acc;
}

// BN affine + ELU on X rows, then @W (known-good 4-row form)
__global__ void bn_elu_mm64_kernel(const float* __restrict__ X, const float* __restrict__ W,
                                   const float* __restrict__ ss, float* __restrict__ Y, int n) {
  __shared__ float Ws[64][64];
  __shared__ float xs[4][64];
  int tid = threadIdx.x;
  for (int i = tid; i < 64 * 64; i += 256) Ws[i >> 6][i & 63] = W[i];
  int rr = tid >> 6, c = tid & 63;
  int row = blockIdx.x * 4 + rr;
  float v = 0.0f;
  if (row < n) {
    v = X[(size_t)row * 64 + c] * ss[c] + ss[64 + c];
    v = v > 0.0f ? v : expm1f(v);
  }
  xs[rr][c] = v;
  __syncthreads();
  float acc = 0.0f;
#pragma unroll
  for (int k = 0; k < 64; ++k) acc = fmaf(xs[rr][k], Ws[k][c], acc);
  if (row < n) Y[(size_t)row * 64 + c] = acc;
}

// Gather core: 1 wave/row, lanes = 4 neighbor-slots x 16 channel-quads.
// EXACT R18 inner loop: k+=4, one float4 load per iter, unroll 4 -> the
// unroller batches 4 shfl-pairs + 4 loads per unrolled body (proven <=48us).
__device__ __forceinline__ float4 gcn_gather_core(
    const int* __restrict__ rowptr, const int* __restrict__ col,
    const float* __restrict__ dinv, const float4* __restrict__ H4,
    int row, int lane, int sub, int cg, bool valid) {
  float4 acc = make_float4(0.f, 0.f, 0.f, 0.f);
  int p0 = 0, p1 = 0;
  if (valid) { p0 = rowptr[row]; p1 = rowptr[row + 1]; }
  for (int base = p0; base < p1; base += 64) {
    int myp = base + lane;
    int j = (myp < p1) ? col[myp] : 0;
    float w = (myp < p1) ? dinv[j] : 0.0f;
    int m = p1 - base;
    m = m < 64 ? m : 64;
#pragma unroll 4
    for (int k = 0; k < m; k += 4) {
      int s = k + sub;               // <= 63 always (k <= 60)
      int jj = __shfl(j, s);
      float ww = __shfl(w, s);       // 0 for tail slots past p1
      float4 hv = H4[(size_t)jj * 16 + cg];
      acc.x = fmaf(hv.x, ww, acc.x);
      acc.y = fmaf(hv.y, ww, acc.y);
      acc.z = fmaf(hv.z, ww, acc.z);
      acc.w = fmaf(hv.w, ww, acc.w);
    }
  }
  acc.x += __shfl_xor(acc.x, 16);
  acc.y += __shfl_xor(acc.y, 16);
  acc.z += __shfl_xor(acc.z, 16);
  acc.w += __shfl_xor(acc.w, 16);
  acc.x += __shfl_xor(acc.x, 32);
  acc.y += __shfl_xor(acc.y, 32);
  acc.z += __shfl_xor(acc.z, 32);
  acc.w += __shfl_xor(acc.w, 32);
  return acc;
}

// gather + BN-stat accumulation (64-replica scratch bnsR[64][128]).
__global__ void gather_bn_kernel(const int* __restrict__ rowptr, const int* __restrict__ col,
                                 const float* __restrict__ dinv, const float* __restrict__ H,
                                 const float* __restrict__ b, float* __restrict__ OUT,
                                 float* __restrict__ bnsR, int n) {
  int wave = threadIdx.x >> 6;
  int lane = threadIdx.x & 63;
  int row = blockIdx.x * 4 + wave;
  bool valid = row < n;
  int sub = lane >> 4;
  int cg = lane & 15;
  const float4* __restrict__ H4 = (const float4*)H;
  float4 acc = gcn_gather_core(rowptr, col, dinv, H4, row, lane, sub, cg, valid);
  float4 o = make_float4(0.f, 0.f, 0.f, 0.f);
  if (valid) {
    float di = dinv[row];
    float d2 = di * di;
    float4 self = H4[(size_t)row * 16 + cg];
    float4 bb = ((const float4*)b)[cg];
    o.x = fmaf(acc.x, di, fmaf(self.x, d2, bb.x));
    o.y = fmaf(acc.y, di, fmaf(self.y, d2, bb.y));
    o.z = fmaf(acc.z, di, fmaf(self.z, d2, bb.z));
    o.w = fmaf(acc.w, di, fmaf(self.w, d2, bb.w));
    if (sub == 0) ((float4*)OUT)[(size_t)row * 16 + cg] = o;
  }
  __shared__ float sA[4][64], sB[4][64];
  if (sub == 0) {
    sA[wave][4 * cg + 0] = o.x;
    sA[wave][4 * cg + 1] = o.y;
    sA[wave][4 * cg + 2] = o.z;
    sA[wave][4 * cg + 3] = o.w;
    sB[wave][4 * cg + 0] = o.x * o.x;
    sB[wave][4 * cg + 1] = o.y * o.y;
    sB[wave][4 * cg + 2] = o.z * o.z;
    sB[wave][4 * cg + 3] = o.w * o.w;
  }
  __syncthreads();
  int t = threadIdx.x;
  if (t < 64) {
    float s = sA[0][t] + sA[1][t] + sA[2][t] + sA[3][t];
    float s2 = sB[0][t] + sB[1][t] + sB[2][t] + sB[3][t];
    float* d = bnsR + (size_t)(blockIdx.x & 63) * 128;
    atomicAdd(&d[t], s);
    atomicAdd(&d[64 + t], s2);
  }
}

// gather + pool accumulation (16-replica scratch poolR[16][4096]).
__global__ void gather_pool_kernel(const int* __restrict__ rowptr, const int* __restrict__ col,
                                   const float* __restrict__ dinv, const float* __restrict__ H,
                                   const float* __restrict__ b, float* __restrict__ OUT,
                                   const int* __restrict__ batch, float* __restrict__ poolR,
                                   int n) {
  int wave = threadIdx.x >> 6;
  int lane = threadIdx.x & 63;
  int row = blockIdx.x * 4 + wave;
  if (row >= n) return;
  int sub = lane >> 4;
  int cg = lane & 15;
  const float4* __restrict__ H4 = (const float4*)H;
  float4 acc = gcn_gather_core(rowptr, col, dinv, H4, row, lane, sub, cg, true);
  float di = dinv[row];
  float d2 = di * di;
  float4 self = H4[(size_t)row * 16 + cg];
  float4 bb = ((const float4*)b)[cg];
  float4 o;
  o.x = fmaf(acc.x, di, fmaf(self.x, d2, bb.x));
  o.y = fmaf(acc.y, di, fmaf(self.y, d2, bb.y));
  o.z = fmaf(acc.z, di, fmaf(self.z, d2, bb.z));
  o.w = fmaf(acc.w, di, fmaf(self.w, d2, bb.w));
  if (sub == 0) {
    ((float4*)OUT)[(size_t)row * 16 + cg] = o;
    int g = batch[row];
    if ((unsigned)g < (unsigned)GGRAPHS) {
      float* d = poolR + (size_t)(blockIdx.x & 15) * 4096 + g * 64 + 4 * cg;
      atomicAdd(d + 0, o.x);
      atomicAdd(d + 1, o.y);
      atomicAdd(d + 2, o.z);
      atomicAdd(d + 3, o.w);
    }
  }
}

// reduce 64 BN replicas -> scale/shift
__global__ void bn_final_kernel(const float* __restrict__ bnsR, const float* __restrict__ gamma,
                                const float* __restrict__ beta, float* __restrict__ ss, int n) {
  __shared__ float red[128];
  int t = threadIdx.x;  // 128 threads
  float s = 0.0f;
  for (int r = 0; r < 64; ++r) s += bnsR[r * 128 + t];
  red[t] = s;
  __syncthreads();
  if (t < 64) {
    float inv_n = 1.0f / (float)n;
    float mu = red[t] * inv_n;
    float var = red[64 + t] * inv_n - mu * mu;
    var = fmaxf(var, 0.0f);
    float sc = gamma[t] * rsqrtf(var + 1e-5f);
    ss[t] = sc;
    ss[64 + t] = beta[t] - mu * sc;
  }
}

// reduce 16 pool replicas, divide by count
__global__ void pool_final_kernel(const float* __restrict__ poolR, const int* __restrict__ cnt,
                                  float* __restrict__ out) {
  int idx = blockIdx.x * 256 + threadIdx.x;  // 4096 total
  float s = 0.0f;
  for (int r = 0; r < 16; ++r) s += poolR[r * 4096 + idx];
  int g = idx >> 6;
  float c = (float)cnt[g];
  out[idx] = s / fmaxf(c, 1.0f);
}

extern "C" void kernel_launch(void* const* d_in, const int* in_sizes, int n_in,
                              void* d_out, int out_size, void* d_ws, size_t ws_size,
                              hipStream_t stream) {
  const float* x = (const float*)d_in[0];
  const int* ei = (const int*)d_in[1];
  const int* batch = (const int*)d_in[2];
  const float* W1 = (const float*)d_in[3];
  const float* b1 = (const float*)d_in[4];
  const float* gamma = (const float*)d_in[5];
  const float* beta = (const float*)d_in[6];
  const float* W2 = (const float*)d_in[7];
  const float* b2 = (const float*)d_in[8];

  const int n = in_sizes[0] / 64;
  const int E = in_sizes[1] / 2;
  const int* srcp = ei;
  const int* dstp = ei + E;

  float* ws = (float*)d_ws;
  size_t nf = (size_t)n * 64;
  float* bufA = ws;                   // h1, then h2' (aliases part/hist in preproc)
  float* bufB = ws + nf;              // pre-BN h
  float* dinv = ws + 2 * nf;          // n floats
  float* ss = dinv + n;               // 128
  int* rowptr = (int*)(ss + 128);     // n+1
  int* col = rowptr + n + 1;          // E
  int* bsum = col + E;                // <=257
  float* bnsR = (float*)(bsum + 257); // 64*128   (zero region starts here)
  float* poolR = bnsR + 64 * 128;     // 16*4096
  int* cnti = (int*)(poolR + 16 * 4096);  // 64   (zero region ends here)

  // preprocessing scratch aliased into bufA (free until mm64)
  int* part = (int*)bufA;             // E packed edges
  int* hist = part + E;               // S+1

  float* out = (float*)d_out;  // FLOAT32 output

  size_t zbytes = (size_t)((char*)(cnti + 64) - (char*)bnsR);
  hipMemsetAsync(bnsR, 0, zbytes, stream);

  int blk = 256;
  int nblkP = (E + EPB - 1) / EPB;    // 98 partition blocks
  int nbuck = (n + 255) >> 8;         // 196 buckets (needs n <= 65536)
  int S = nbuck * nblkP;              // 19208 counters
  int nbt = (S + 255) / 256;          // 76 scan tiles (<= 256)
  int gridRows = (n + 3) / 4;

  phist_kernel<<<nblkP, blk, 0, stream>>>(dstp, hist, E, n, nblkP, nbuck);
  cnt_kernel<<<128, blk, 0, stream>>>(batch, cnti, n);
  scan1_kernel<<<nbt, blk, 0, stream>>>(hist, hist, bsum, S);
  scan2_kernel<<<1, blk, 0, stream>>>(bsum, nbt);
  scan_add_kernel<<<nbt, blk, 0, stream>>>(hist, bsum, S, nbt);
  part_kernel<<<nblkP, blk, 0, stream>>>(srcp, dstp, hist, part, E, n, nblkP, nbuck);
  csr_kernel<<<nbuck, blk, 0, stream>>>(part, hist, rowptr, dinv, col, n, nblkP, nbuck);

  mm64_kernel<<<gridRows, blk, 0, stream>>>(x, W1, bufA, n);
  gather_bn_kernel<<<gridRows, blk, 0, stream>>>(rowptr, col, dinv, bufA, b1, bufB, bnsR, n);
  bn_final_kernel<<<1, 128, 0, stream>>>(bnsR, gamma, beta, ss, n);
  bn_elu_mm64_kernel<<<gridRows, blk, 0, stream>>>(bufB, W2, ss, bufA, n);
  gather_pool_kernel<<<gridRows, blk, 0, stream>>>(rowptr, col, dinv, bufA, b2, out, batch,
                                                   poolR, n);
  pool_final_kernel<<<16, blk, 0, stream>>>(poolR, cnti, out + nf);
}

// Round 6
// 276.189 us; speedup vs baseline: 2.7251x; 1.4279x over previous
//
#include <hip/hip_runtime.h>

// GCNEncoder: 2x GCNConv(64->64) + BatchNorm + ELU + global_mean_pool
// N=50000, E=800000, D=64, G=64. Inputs f32/int32, output f32.
// R18 324.1 -> R19 284.2 (counting-sort CSR, unfused stats/pool).
// R20-R22 regression chain RESOLVED: it was never the matmul shape nor the
//   gather inner loop -- the fused epilogues issued PER-ROW global atomics:
//   pool = 3.2M atomics / 1024 hot addrs (sorted batch) = 3125-long chains
//   ~ 40-50ns each ~ 125-155us (matches gather_pool 166us + 5x WRITE_SIZE);
//   bn = 195-long chains ~ +10us (matches gather_bn ~58us by subtraction).
// R23: keep fusion, restore R19 aggregation granularity: gather_pool
//   pre-reduces its 4 (sorted) rows in LDS -> 64 atomics/block to 16
//   replicas (chains ~12); bnsR spread over 256 replicas (chains ~49).
//   Gather core / matmuls / CSR build byte-identical to R22.

constexpr int GGRAPHS = 64;
constexpr int EPB = 8192;  // edges per partition block

// cnt[g] via per-block LDS histogram (batch sorted -> storms stay in LDS)
__global__ void cnt_kernel(const int* __restrict__ batch, int* __restrict__ cnt, int n) {
  __shared__ int h[GGRAPHS];
  int t = threadIdx.x;
  if (t < GGRAPHS) h[t] = 0;
  __syncthreads();
  for (int i = blockIdx.x * 256 + t; i < n; i += gridDim.x * 256) {
    int g = batch[i];
    if ((unsigned)g < (unsigned)GGRAPHS) atomicAdd(&h[g], 1);
  }
  __syncthreads();
  if (t < GGRAPHS && h[t] > 0) atomicAdd(&cnt[t], h[t]);
}

// P1: per-block bucket histogram. hist[b*nblk + blk] = #edges of block blk
// with dst in bucket b (bucket = dst>>8, nbuck <= 256 for n <= 65536).
__global__ void phist_kernel(const int* __restrict__ dst, int* __restrict__ hist,
                             int E, int n, int nblk, int nbuck) {
  __shared__ int h[256];
  int t = threadIdx.x;
  h[t] = 0;
  __syncthreads();
  int e0 = blockIdx.x * EPB;
  int e1 = e0 + EPB < E ? e0 + EPB : E;
  for (int i = e0 + t; i < e1; i += 256) {
    int d = dst[i];
    if ((unsigned)d < (unsigned)n) atomicAdd(&h[d >> 8], 1);
  }
  __syncthreads();
  if (t < nbuck) hist[t * nblk + blockIdx.x] = h[t];
}

// scan pass 1: per-256-tile exclusive scan; out[i]=local excl, bsum[b]=tile total.
__global__ void scan1_kernel(const int* __restrict__ in, int* __restrict__ out,
                             int* __restrict__ bsum, int n) {
  __shared__ int tmp[256];
  int t = threadIdx.x;
  int i = blockIdx.x * 256 + t;
  int v = (i < n) ? in[i] : 0;
  tmp[t] = v;
  __syncthreads();
#pragma unroll
  for (int off = 1; off < 256; off <<= 1) {
    int a = (t >= off) ? tmp[t - off] : 0;
    __syncthreads();
    tmp[t] += a;
    __syncthreads();
  }
  if (i < n) out[i] = tmp[t] - v;  // exclusive
  if (t == 255) bsum[blockIdx.x] = tmp[255];
}

// scan pass 2: 1 block, exclusive scan of bsum[nb] (nb <= 256); bsum[nb] = total.
__global__ void scan2_kernel(int* __restrict__ bsum, int nb) {
  __shared__ int tmp[256];
  int t = threadIdx.x;
  int v = (t < nb) ? bsum[t] : 0;
  tmp[t] = v;
  __syncthreads();
#pragma unroll
  for (int off = 1; off < 256; off <<= 1) {
    int a = (t >= off) ? tmp[t - off] : 0;
    __syncthreads();
    tmp[t] += a;
    __syncthreads();
  }
  if (t < nb) bsum[t] = tmp[t] - v;
  if (t == 255) bsum[nb] = tmp[255];
}

// scan pass 3: data[i] += bsum[tile]; data[S] = grand total.
__global__ void scan_add_kernel(int* __restrict__ data, const int* __restrict__ bsum,
                                int S, int nbt) {
  int i = blockIdx.x * 256 + threadIdx.x;
  if (i < S) data[i] += bsum[blockIdx.x];
  if (i == 0) data[S] = bsum[nbt];
}

// P3: scatter edges into bucket-partitioned array, packed (src<<8)|(dst&255).
__global__ void part_kernel(const int* __restrict__ srcp, const int* __restrict__ dstp,
                            const int* __restrict__ hist, int* __restrict__ part,
                            int E, int n, int nblk, int nbuck) {
  __shared__ int cur[256];
  int t = threadIdx.x;
  if (t < nbuck) cur[t] = hist[t * nblk + blockIdx.x];
  __syncthreads();
  int e0 = blockIdx.x * EPB;
  int e1 = e0 + EPB < E ? e0 + EPB : E;
  for (int i = e0 + t; i < e1; i += 256) {
    int d = dstp[i];
    if ((unsigned)d >= (unsigned)n) continue;
    int s = srcp[i];
    int pos = atomicAdd(&cur[d >> 8], 1);
    part[pos] = (s << 8) | (d & 255);
  }
}

// P4: one block per bucket (256 nodes). LDS degree -> LDS scan -> rowptr/dinv
// coalesced -> col placed via LDS cursors (writes stay in 16KB segment).
__global__ void csr_kernel(const int* __restrict__ part, const int* __restrict__ hist,
                           int* __restrict__ rowptr, float* __restrict__ dinv,
                           int* __restrict__ col, int n, int nblk, int nbuck) {
  __shared__ int degL[256], scn[256], cur[256];
  int t = threadIdx.x;
  int b = blockIdx.x;
  degL[t] = 0;
  cur[t] = 0;
  __syncthreads();
  int base = hist[b * nblk];
  int end = hist[(b + 1) * nblk];  // hist[S] = total for last bucket
  for (int i = base + t; i < end; i += 256) atomicAdd(&degL[part[i] & 255], 1);
  __syncthreads();
  int dv = degL[t];
  scn[t] = dv;
  __syncthreads();
#pragma unroll
  for (int off = 1; off < 256; off <<= 1) {
    int a = (t >= off) ? scn[t - off] : 0;
    __syncthreads();
    scn[t] += a;
    __syncthreads();
  }
  int excl = scn[t] - dv;
  int node = (b << 8) + t;
  if (node < n) {
    rowptr[node] = base + excl;
    dinv[node] = rsqrtf((float)dv + 1.0f);
  }
  if (b == nbuck - 1 && t == 0) rowptr[n] = end;
  scn[t] = excl;
  __syncthreads();
  for (int i = base + t; i < end; i += 256) {
    int u = part[i];
    int d = u & 255;
    int k = atomicAdd(&cur[d], 1);
    col[base + scn[d] + k] = u >> 8;
  }
}

// Y[n,64] = X[n,64] @ W[64,64]; block = 4 rows x 64 cols (known-good)
__global__ void mm64_kernel(const float* __restrict__ X, const float* __restrict__ W,
                            float* __restrict__ Y, int n) {
  __shared__ float Ws[64][64];
  __shared__ float xs[4][64];
  int tid = threadIdx.x;
  for (int i = tid; i < 64 * 64; i += 256) Ws[i >> 6][i & 63] = W[i];
  int rr = tid >> 6, c = tid & 63;
  int row = blockIdx.x * 4 + rr;
  xs[rr][c] = (row < n) ? X[(size_t)row * 64 + c] : 0.0f;
  __syncthreads();
  float acc = 0.0f;
#pragma unroll
  for (int k = 0; k < 64; ++k) acc = fmaf(xs[rr][k], Ws[k][c], acc);
  if (row < n) Y[(size_t)row * 64 + c] = acc;
}

// BN affine + ELU on X rows, then @W (known-good 4-row form)
__global__ void bn_elu_mm64_kernel(const float* __restrict__ X, const float* __restrict__ W,
                                   const float* __restrict__ ss, float* __restrict__ Y, int n) {
  __shared__ float Ws[64][64];
  __shared__ float xs[4][64];
  int tid = threadIdx.x;
  for (int i = tid; i < 64 * 64; i += 256) Ws[i >> 6][i & 63] = W[i];
  int rr = tid >> 6, c = tid & 63;
  int row = blockIdx.x * 4 + rr;
  float v = 0.0f;
  if (row < n) {
    v = X[(size_t)row * 64 + c] * ss[c] + ss[64 + c];
    v = v > 0.0f ? v : expm1f(v);
  }
  xs[rr][c] = v;
  __syncthreads();
  float acc = 0.0f;
#pragma unroll
  for (int k = 0; k < 64; ++k) acc = fmaf(xs[rr][k], Ws[k][c], acc);
  if (row < n) Y[(size_t)row * 64 + c] = acc;
}

// Gather core: 1 wave/row, lanes = 4 neighbor-slots x 16 channel-quads.
// R18-proven inner loop: k+=4, one float4 load per iter, unroll 4.
__device__ __forceinline__ float4 gcn_gather_core(
    const int* __restrict__ rowptr, const int* __restrict__ col,
    const float* __restrict__ dinv, const float4* __restrict__ H4,
    int row, int lane, int sub, int cg, bool valid) {
  float4 acc = make_float4(0.f, 0.f, 0.f, 0.f);
  int p0 = 0, p1 = 0;
  if (valid) { p0 = rowptr[row]; p1 = rowptr[row + 1]; }
  for (int base = p0; base < p1; base += 64) {
    int myp = base + lane;
    int j = (myp < p1) ? col[myp] : 0;
    float w = (myp < p1) ? dinv[j] : 0.0f;
    int m = p1 - base;
    m = m < 64 ? m : 64;
#pragma unroll 4
    for (int k = 0; k < m; k += 4) {
      int s = k + sub;               // <= 63 always (k <= 60)
      int jj = __shfl(j, s);
      float ww = __shfl(w, s);       // 0 for tail slots past p1
      float4 hv = H4[(size_t)jj * 16 + cg];
      acc.x = fmaf(hv.x, ww, acc.x);
      acc.y = fmaf(hv.y, ww, acc.y);
      acc.z = fmaf(hv.z, ww, acc.z);
      acc.w = fmaf(hv.w, ww, acc.w);
    }
  }
  acc.x += __shfl_xor(acc.x, 16);
  acc.y += __shfl_xor(acc.y, 16);
  acc.z += __shfl_xor(acc.z, 16);
  acc.w += __shfl_xor(acc.w, 16);
  acc.x += __shfl_xor(acc.x, 32);
  acc.y += __shfl_xor(acc.y, 32);
  acc.z += __shfl_xor(acc.z, 32);
  acc.w += __shfl_xor(acc.w, 32);
  return acc;
}

// gather + BN-stat accumulation (256-replica scratch bnsR[256][128]).
__global__ void gather_bn_kernel(const int* __restrict__ rowptr, const int* __restrict__ col,
                                 const float* __restrict__ dinv, const float* __restrict__ H,
                                 const float* __restrict__ b, float* __restrict__ OUT,
                                 float* __restrict__ bnsR, int n) {
  int wave = threadIdx.x >> 6;
  int lane = threadIdx.x & 63;
  int row = blockIdx.x * 4 + wave;
  bool valid = row < n;
  int sub = lane >> 4;
  int cg = lane & 15;
  const float4* __restrict__ H4 = (const float4*)H;
  float4 acc = gcn_gather_core(rowptr, col, dinv, H4, row, lane, sub, cg, valid);
  float4 o = make_float4(0.f, 0.f, 0.f, 0.f);
  if (valid) {
    float di = dinv[row];
    float d2 = di * di;
    float4 self = H4[(size_t)row * 16 + cg];
    float4 bb = ((const float4*)b)[cg];
    o.x = fmaf(acc.x, di, fmaf(self.x, d2, bb.x));
    o.y = fmaf(acc.y, di, fmaf(self.y, d2, bb.y));
    o.z = fmaf(acc.z, di, fmaf(self.z, d2, bb.z));
    o.w = fmaf(acc.w, di, fmaf(self.w, d2, bb.w));
    if (sub == 0) ((float4*)OUT)[(size_t)row * 16 + cg] = o;
  }
  __shared__ float sA[4][64], sB[4][64];
  if (sub == 0) {
    sA[wave][4 * cg + 0] = o.x;
    sA[wave][4 * cg + 1] = o.y;
    sA[wave][4 * cg + 2] = o.z;
    sA[wave][4 * cg + 3] = o.w;
    sB[wave][4 * cg + 0] = o.x * o.x;
    sB[wave][4 * cg + 1] = o.y * o.y;
    sB[wave][4 * cg + 2] = o.z * o.z;
    sB[wave][4 * cg + 3] = o.w * o.w;
  }
  __syncthreads();
  int t = threadIdx.x;
  if (t < 64) {
    float s = sA[0][t] + sA[1][t] + sA[2][t] + sA[3][t];
    float s2 = sB[0][t] + sB[1][t] + sB[2][t] + sB[3][t];
    float* d = bnsR + (size_t)(blockIdx.x & 255) * 128;
    atomicAdd(&d[t], s);
    atomicAdd(&d[64 + t], s2);
  }
}

// gather + pool accumulation: LDS pre-reduce the block's 4 (sorted) rows,
// then 64 atomics/block to one of 16 replicas (chains ~12 vs R22's ~3125).
__global__ void gather_pool_kernel(const int* __restrict__ rowptr, const int* __restrict__ col,
                                   const float* __restrict__ dinv, const float* __restrict__ H,
                                   const float* __restrict__ b, float* __restrict__ OUT,
                                   const int* __restrict__ batch, float* __restrict__ poolR,
                                   int n) {
  int wave = threadIdx.x >> 6;
  int lane = threadIdx.x & 63;
  int row = blockIdx.x * 4 + wave;
  bool valid = row < n;
  int sub = lane >> 4;
  int cg = lane & 15;
  const float4* __restrict__ H4 = (const float4*)H;
  float4 acc = gcn_gather_core(rowptr, col, dinv, H4, row, lane, sub, cg, valid);
  float4 o = make_float4(0.f, 0.f, 0.f, 0.f);
  __shared__ float sO[4][64];
  __shared__ int sG[4];
  if (valid) {
    float di = dinv[row];
    float d2 = di * di;
    float4 self = H4[(size_t)row * 16 + cg];
    float4 bb = ((const float4*)b)[cg];
    o.x = fmaf(acc.x, di, fmaf(self.x, d2, bb.x));
    o.y = fmaf(acc.y, di, fmaf(self.y, d2, bb.y));
    o.z = fmaf(acc.z, di, fmaf(self.z, d2, bb.z));
    o.w = fmaf(acc.w, di, fmaf(self.w, d2, bb.w));
    if (sub == 0) ((float4*)OUT)[(size_t)row * 16 + cg] = o;
  }
  if (lane == 0) {
    int g = valid ? batch[row] : -1;
    sG[wave] = ((unsigned)g < (unsigned)GGRAPHS) ? g : -1;
  }
  if (sub == 0) {
    sO[wave][4 * cg + 0] = o.x;
    sO[wave][4 * cg + 1] = o.y;
    sO[wave][4 * cg + 2] = o.z;
    sO[wave][4 * cg + 3] = o.w;
  }
  __syncthreads();
  int t = threadIdx.x;
  if (t < 64) {
    float* base = poolR + (size_t)(blockIdx.x & 15) * 4096;
    int g0 = sG[0];
    float s0 = 0.0f;
#pragma unroll
    for (int w = 0; w < 4; ++w) {
      int gw = sG[w];
      if (gw < 0) continue;
      if (gw == g0) s0 += sO[w][t];
      else atomicAdd(&base[gw * 64 + t], sO[w][t]);  // rare: graph boundary
    }
    if (g0 >= 0) atomicAdd(&base[g0 * 64 + t], s0);
  }
}

// reduce 256 BN replicas -> scale/shift
__global__ void bn_final_kernel(const float* __restrict__ bnsR, const float* __restrict__ gamma,
                                const float* __restrict__ beta, float* __restrict__ ss, int n) {
  __shared__ float red[128];
  int t = threadIdx.x;  // 128 threads
  float s = 0.0f;
  for (int r = 0; r < 256; ++r) s += bnsR[r * 128 + t];
  red[t] = s;
  __syncthreads();
  if (t < 64) {
    float inv_n = 1.0f / (float)n;
    float mu = red[t] * inv_n;
    float var = red[64 + t] * inv_n - mu * mu;
    var = fmaxf(var, 0.0f);
    float sc = gamma[t] * rsqrtf(var + 1e-5f);
    ss[t] = sc;
    ss[64 + t] = beta[t] - mu * sc;
  }
}

// reduce 16 pool replicas, divide by count
__global__ void pool_final_kernel(const float* __restrict__ poolR, const int* __restrict__ cnt,
                                  float* __restrict__ out) {
  int idx = blockIdx.x * 256 + threadIdx.x;  // 4096 total
  float s = 0.0f;
  for (int r = 0; r < 16; ++r) s += poolR[r * 4096 + idx];
  int g = idx >> 6;
  float c = (float)cnt[g];
  out[idx] = s / fmaxf(c, 1.0f);
}

extern "C" void kernel_launch(void* const* d_in, const int* in_sizes, int n_in,
                              void* d_out, int out_size, void* d_ws, size_t ws_size,
                              hipStream_t stream) {
  const float* x = (const float*)d_in[0];
  const int* ei = (const int*)d_in[1];
  const int* batch = (const int*)d_in[2];
  const float* W1 = (const float*)d_in[3];
  const float* b1 = (const float*)d_in[4];
  const float* gamma = (const float*)d_in[5];
  const float* beta = (const float*)d_in[6];
  const float* W2 = (const float*)d_in[7];
  const float* b2 = (const float*)d_in[8];

  const int n = in_sizes[0] / 64;
  const int E = in_sizes[1] / 2;
  const int* srcp = ei;
  const int* dstp = ei + E;

  float* ws = (float*)d_ws;
  size_t nf = (size_t)n * 64;
  float* bufA = ws;                   // h1, then h2' (aliases part/hist in preproc)
  float* bufB = ws + nf;              // pre-BN h
  float* dinv = ws + 2 * nf;          // n floats
  float* ss = dinv + n;               // 128
  int* rowptr = (int*)(ss + 128);     // n+1
  int* col = rowptr + n + 1;          // E
  int* bsum = col + E;                // <=257
  float* bnsR = (float*)(bsum + 257); // 256*128  (zero region starts here)
  float* poolR = bnsR + 256 * 128;    // 16*4096
  int* cnti = (int*)(poolR + 16 * 4096);  // 64   (zero region ends here)

  // preprocessing scratch aliased into bufA (free until mm64)
  int* part = (int*)bufA;             // E packed edges
  int* hist = part + E;               // S+1

  float* out = (float*)d_out;  // FLOAT32 output

  size_t zbytes = (size_t)((char*)(cnti + 64) - (char*)bnsR);
  hipMemsetAsync(bnsR, 0, zbytes, stream);

  int blk = 256;
  int nblkP = (E + EPB - 1) / EPB;    // 98 partition blocks
  int nbuck = (n + 255) >> 8;         // 196 buckets (needs n <= 65536)
  int S = nbuck * nblkP;              // 19208 counters
  int nbt = (S + 255) / 256;          // 76 scan tiles (<= 256)
  int gridRows = (n + 3) / 4;

  phist_kernel<<<nblkP, blk, 0, stream>>>(dstp, hist, E, n, nblkP, nbuck);
  cnt_kernel<<<128, blk, 0, stream>>>(batch, cnti, n);
  scan1_kernel<<<nbt, blk, 0, stream>>>(hist, hist, bsum, S);
  scan2_kernel<<<1, blk, 0, stream>>>(bsum, nbt);
  scan_add_kernel<<<nbt, blk, 0, stream>>>(hist, bsum, S, nbt);
  part_kernel<<<nblkP, blk, 0, stream>>>(srcp, dstp, hist, part, E, n, nblkP, nbuck);
  csr_kernel<<<nbuck, blk, 0, stream>>>(part, hist, rowptr, dinv, col, n, nblkP, nbuck);

  mm64_kernel<<<gridRows, blk, 0, stream>>>(x, W1, bufA, n);
  gather_bn_kernel<<<gridRows, blk, 0, stream>>>(rowptr, col, dinv, bufA, b1, bufB, bnsR, n);
  bn_final_kernel<<<1, 128, 0, stream>>>(bnsR, gamma, beta, ss, n);
  bn_elu_mm64_kernel<<<gridRows, blk, 0, stream>>>(bufB, W2, ss, bufA, n);
  gather_pool_kernel<<<gridRows, blk, 0, stream>>>(rowptr, col, dinv, bufA, b2, out, batch,
                                                   poolR, n);
  pool_final_kernel<<<16, blk, 0, stream>>>(poolR, cnti, out + nf);
}